// Round 6
// baseline (1268.889 us; speedup 1.0000x reference)
//
#include <hip/hip_runtime.h>
#include <hip/hip_bf16.h>
#include <hip/hip_cooperative_groups.h>
#include <math.h>

#define HID 512
#define WCW_LD 576

namespace cg = cooperative_groups;

typedef unsigned short u16;
typedef __attribute__((ext_vector_type(8))) short bf16x8;
typedef __attribute__((ext_vector_type(4))) float f32x4;

__device__ __forceinline__ u16 f2bf(float f) {
    union { float f; unsigned u; } x; x.f = f;
    unsigned r = x.u + 0x7fffu + ((x.u >> 16) & 1u);
    return (u16)(r >> 16);
}
__device__ __forceinline__ float bf2f(u16 b) {
    union { unsigned u; float f; } x; x.u = ((unsigned)b) << 16; return x.f;
}
__device__ __forceinline__ float sigm(float x) { return 1.f / (1.f + expf(-x)); }

// XOR swizzle within 128-B windows (row stride multiple of 128 B)
__device__ __forceinline__ int swz(int row, int byte) { return byte ^ ((row & 7) << 4); }

// ---------------------------------------------------------------------------
// Pe[v][j] = emb[v].Wc_e[j] + Wc_b[j]  (fp32) ; PeT16 = bf16(tanh(Pe))
__global__ void pe_kernel(const float* __restrict__ emb, const float* __restrict__ Wc_w,
                          const float* __restrict__ Wc_b, float* __restrict__ Pe,
                          u16* __restrict__ PeT16) {
    int v = blockIdx.x, j = threadIdx.x;
    __shared__ float e[64];
    if (threadIdx.x < 64) e[threadIdx.x] = emb[v * 64 + threadIdx.x];
    __syncthreads();
    float acc = Wc_b[j];
    const float* w = Wc_w + (long long)j * WCW_LD;
#pragma unroll 8
    for (int k = 0; k < 64; ++k) acc += e[k] * w[k];
    Pe[v * HID + j] = acc;
    PeT16[v * HID + j] = f2bf(tanhf(acc));
}

__global__ void conv_w_kernel(const float* __restrict__ W_ih, const float* __restrict__ W_hh,
                              const float* __restrict__ Wc_w,
                              u16* __restrict__ Wih16, u16* __restrict__ Whh16,
                              u16* __restrict__ Wch16) {
    int idx = blockIdx.x * blockDim.x + threadIdx.x;
    int stride = gridDim.x * blockDim.x;
    for (int i = idx; i < 3 * HID * HID; i += stride) {
        Wih16[i] = f2bf(W_ih[i]);
        Whh16[i] = f2bf(W_hh[i]);
    }
    for (int i = idx; i < HID * HID; i += stride) {
        int j = i >> 9, k = i & 511;
        Wch16[i] = f2bf(Wc_w[(long long)j * WCW_LD + 64 + k]);
    }
}

// ---------------------------------------------------------------------------
// Gx = A @ Wih^T + b_ih  -> bf16 [M x 1536]. 128x64 tile, 4 waves.
// GATHER: A row m = PeT16[nt[4681+m]] (leaf fold); else A row m = Asrc[m].
template<bool GATHER>
__global__ __launch_bounds__(256)
void gx_gemm(const u16* __restrict__ Asrc, const u16* __restrict__ PeT16,
             const int* __restrict__ nt, const u16* __restrict__ Wih16,
             const float* __restrict__ b_ih, u16* __restrict__ gx16, int M) {
    __shared__ __align__(16) uint8_t sA[128 * 128];
    __shared__ __align__(16) uint8_t sB[64 * 128];
    int tid = threadIdx.x, lane = tid & 63, w = tid >> 6;
    int j0 = blockIdx.x * 64;
    int m0 = blockIdx.y * 128;

    f32x4 acc[2][4];
#pragma unroll
    for (int m = 0; m < 2; ++m)
#pragma unroll
        for (int jf = 0; jf < 4; ++jf) acc[m][jf] = (f32x4){0.f, 0.f, 0.f, 0.f};

    for (int k0 = 0; k0 < HID; k0 += 64) {
#pragma unroll
        for (int l = 0; l < 4; ++l) {
            int e = tid + l * 256;
            int r = e >> 3, c = e & 7;
            int gm = m0 + r;
            uint4 v = make_uint4(0u, 0u, 0u, 0u);
            if (gm < M) {
                const u16* src = GATHER ? (PeT16 + (long long)nt[4681 + gm] * HID)
                                        : (Asrc + (long long)gm * HID);
                v = *(const uint4*)(src + k0 + c * 8);
            }
            *(uint4*)(sA + r * 128 + swz(r, c * 16)) = v;
        }
#pragma unroll
        for (int l = 0; l < 2; ++l) {
            int e = tid + l * 256;
            int r = e >> 3, c = e & 7;
            uint4 v = *(const uint4*)(Wih16 + (long long)(j0 + r) * HID + k0 + c * 8);
            *(uint4*)(sB + r * 128 + swz(r, c * 16)) = v;
        }
        __syncthreads();
#pragma unroll
        for (int ks = 0; ks < 2; ++ks) {
            int kb = ks * 64 + ((lane >> 4) << 4);
            int ar = lane & 15;
            bf16x8 a0 = *(const bf16x8*)(sA + (w * 32 + ar) * 128 + swz(ar, kb));
            bf16x8 a1 = *(const bf16x8*)(sA + (w * 32 + 16 + ar) * 128 + swz(ar, kb));
#pragma unroll
            for (int jf = 0; jf < 4; ++jf) {
                bf16x8 b = *(const bf16x8*)(sB + (jf * 16 + ar) * 128 + swz(ar, kb));
                acc[0][jf] = __builtin_amdgcn_mfma_f32_16x16x32_bf16(a0, b, acc[0][jf], 0, 0, 0);
                acc[1][jf] = __builtin_amdgcn_mfma_f32_16x16x32_bf16(a1, b, acc[1][jf], 0, 0, 0);
            }
        }
        __syncthreads();
    }

#pragma unroll
    for (int jf = 0; jf < 4; ++jf) {
        int j = j0 + jf * 16 + (lane & 15);
        float bias = b_ih[j];
#pragma unroll
        for (int m = 0; m < 2; ++m) {
#pragma unroll
            for (int q = 0; q < 4; ++q) {
                int row = m0 + w * 32 + m * 16 + (lane >> 4) * 4 + q;
                if (row < M) gx16[(long long)row * 1536 + j] = f2bf(acc[m][jf][q] + bias);
            }
        }
    }
}

// ---------------------------------------------------------------------------
// h-side GRU step, MFMA (level 4, n=4096): 3 gate GEMMs + update. 64x64 tile.
__global__ __launch_bounds__(256, 4)
void gru_step_h(const u16* __restrict__ gx16, int t,
                const float* __restrict__ hsrc_f, const u16* __restrict__ hsrc16,
                float* __restrict__ hdst_f, u16* __restrict__ hdst16,
                const u16* __restrict__ Whh16, const float* __restrict__ b_hh,
                int n, int has_h) {
    __shared__ __align__(16) uint8_t sm[4][8192];
    int tid = threadIdx.x;
    int p0 = blockIdx.x * 64, j0 = blockIdx.y * 64;
    int lane = tid & 63, w = tid >> 6, wr = w >> 1, wc = w & 1;

    f32x4 acc[3][2][2];
#pragma unroll
    for (int g = 0; g < 3; ++g)
#pragma unroll
        for (int i = 0; i < 2; ++i)
#pragma unroll
            for (int j = 0; j < 2; ++j) acc[g][i][j] = (f32x4){0.f, 0.f, 0.f, 0.f};

    if (has_h) {
        for (int kt = 0; kt < 8; ++kt) {
            int k0 = kt * 64;
#pragma unroll
            for (int l = 0; l < 2; ++l) {
                int e = tid + l * 256;
                int r = e >> 3, c = e & 7;
                uint4 v = make_uint4(0u, 0u, 0u, 0u);
                if (p0 + r < n) v = *(const uint4*)(hsrc16 + (long long)(p0 + r) * HID + k0 + c * 8);
                *(uint4*)(sm[0] + r * 128 + swz(r, c * 16)) = v;
            }
#pragma unroll
            for (int g = 0; g < 3; ++g) {
#pragma unroll
                for (int l = 0; l < 2; ++l) {
                    int e = tid + l * 256;
                    int r = e >> 3, c = e & 7;
                    uint4 v = *(const uint4*)(Whh16 + (long long)(g * HID + j0 + r) * HID + k0 + c * 8);
                    *(uint4*)(sm[1 + g] + r * 128 + swz(r, c * 16)) = v;
                }
            }
            __syncthreads();
#pragma unroll
            for (int s = 0; s < 2; ++s) {
                int kb = s * 64 + ((lane >> 4) << 4);
                int ar = lane & 15;
                bf16x8 a0 = *(const bf16x8*)(sm[0] + (wr * 32 + ar) * 128 + swz(ar, kb));
                bf16x8 a1 = *(const bf16x8*)(sm[0] + (wr * 32 + 16 + ar) * 128 + swz(ar, kb));
#pragma unroll
                for (int g = 0; g < 3; ++g) {
#pragma unroll
                    for (int jf = 0; jf < 2; ++jf) {
                        bf16x8 b = *(const bf16x8*)(sm[1 + g] + (wc * 32 + jf * 16 + ar) * 128 + swz(ar, kb));
                        acc[g][0][jf] = __builtin_amdgcn_mfma_f32_16x16x32_bf16(a0, b, acc[g][0][jf], 0, 0, 0);
                        acc[g][1][jf] = __builtin_amdgcn_mfma_f32_16x16x32_bf16(a1, b, acc[g][1][jf], 0, 0, 0);
                    }
                }
            }
            __syncthreads();
        }
    }

#pragma unroll
    for (int i = 0; i < 2; ++i) {
#pragma unroll
        for (int jf = 0; jf < 2; ++jf) {
            int jj = j0 + wc * 32 + jf * 16 + (lane & 15);
            float bhr = b_hh[jj], bhz = b_hh[HID + jj], bhn = b_hh[2 * HID + jj];
#pragma unroll
            for (int q = 0; q < 4; ++q) {
                int p = p0 + wr * 32 + i * 16 + (lane >> 4) * 4 + q;
                if (p >= n) continue;
                long long gb = ((long long)(p * 8 + t)) * 1536 + jj;
                float xr = bf2f(gx16[gb]), xz = bf2f(gx16[gb + 512]), xn = bf2f(gx16[gb + 1024]);
                float r = sigm(xr + acc[0][i][jf][q] + bhr);
                float z = sigm(xz + acc[1][i][jf][q] + bhz);
                float cand = tanhf(xn + r * (acc[2][i][jf][q] + bhn));
                float hp = has_h ? hsrc_f[(long long)p * HID + jj] : 0.f;
                float hnew = (1.f - z) * cand + z * hp;
                hdst_f[(long long)p * HID + jj] = hnew;
                hdst16[(long long)p * HID + jj] = f2bf(hnew);
            }
        }
    }
}

// ---------------------------------------------------------------------------
// MFMA combine (level 4): enc16 = bf16(tanh(Pe[nt] + h @ Wc_h^T))
__global__ __launch_bounds__(256, 4)
void combine_mfma(const u16* __restrict__ enc_in, const u16* __restrict__ Wch16,
                  const int* __restrict__ nt, int off, const float* __restrict__ Pe,
                  u16* __restrict__ out16, int n) {
    __shared__ __align__(16) uint8_t sm[2][8192];
    int tid = threadIdx.x;
    int p0 = blockIdx.x * 64, j0 = blockIdx.y * 64;
    int lane = tid & 63, w = tid >> 6, wr = w >> 1, wc = w & 1;

    f32x4 acc[2][2];
#pragma unroll
    for (int i = 0; i < 2; ++i)
#pragma unroll
        for (int j = 0; j < 2; ++j) acc[i][j] = (f32x4){0.f, 0.f, 0.f, 0.f};

    for (int kt = 0; kt < 8; ++kt) {
        int k0 = kt * 64;
#pragma unroll
        for (int l = 0; l < 2; ++l) {
            int e = tid + l * 256;
            int r = e >> 3, c = e & 7;
            uint4 v = make_uint4(0u, 0u, 0u, 0u);
            if (p0 + r < n) v = *(const uint4*)(enc_in + (long long)(p0 + r) * HID + k0 + c * 8);
            *(uint4*)(sm[0] + r * 128 + swz(r, c * 16)) = v;
        }
#pragma unroll
        for (int l = 0; l < 2; ++l) {
            int e = tid + l * 256;
            int r = e >> 3, c = e & 7;
            uint4 v = *(const uint4*)(Wch16 + (long long)(j0 + r) * HID + k0 + c * 8);
            *(uint4*)(sm[1] + r * 128 + swz(r, c * 16)) = v;
        }
        __syncthreads();
#pragma unroll
        for (int s = 0; s < 2; ++s) {
            int kb = s * 64 + ((lane >> 4) << 4);
            int ar = lane & 15;
            bf16x8 a0 = *(const bf16x8*)(sm[0] + (wr * 32 + ar) * 128 + swz(ar, kb));
            bf16x8 a1 = *(const bf16x8*)(sm[0] + (wr * 32 + 16 + ar) * 128 + swz(ar, kb));
#pragma unroll
            for (int j = 0; j < 2; ++j) {
                bf16x8 b = *(const bf16x8*)(sm[1] + (wc * 32 + j * 16 + ar) * 128 + swz(ar, kb));
                acc[0][j] = __builtin_amdgcn_mfma_f32_16x16x32_bf16(a0, b, acc[0][j], 0, 0, 0);
                acc[1][j] = __builtin_amdgcn_mfma_f32_16x16x32_bf16(a1, b, acc[1][j], 0, 0, 0);
            }
        }
        __syncthreads();
    }

#pragma unroll
    for (int i = 0; i < 2; ++i) {
#pragma unroll
        for (int j = 0; j < 2; ++j) {
            int jj = j0 + wc * 32 + j * 16 + (lane & 15);
#pragma unroll
            for (int q = 0; q < 4; ++q) {
                int p = p0 + wr * 32 + i * 16 + (lane >> 4) * 4 + q;
                if (p >= n) continue;
                int tv = nt[off + p];
                float v = tanhf(Pe[(long long)tv * HID + jj] + acc[i][j][q]);
                out16[(long long)p * HID + jj] = f2bf(v);
            }
        }
    }
}

// ---------------------------------------------------------------------------
// Cooperative tail: levels 3..0 (n = 512, 64, 8, 1).
//   per level: [gx phase for d<3] -> 8 GRU steps -> combine, grid.sync between.
// Each MFMA tile-job accumulates all 3 gates so the GRU update is inline.
__global__ __launch_bounds__(256)
void tail_kernel(u16* gx, const u16* __restrict__ Wih16, const u16* __restrict__ Whh16,
                 const u16* __restrict__ Wch16, const float* __restrict__ b_ih,
                 const float* __restrict__ b_hh, const int* __restrict__ nt,
                 const float* __restrict__ Pe, u16* enc16,
                 float* Hf, u16* H16, float* outf) {
    cg::grid_group gg = cg::this_grid();
    int tid = threadIdx.x, lane = tid & 63;
    int wave = blockIdx.x * 4 + (tid >> 6);
    int nw = gridDim.x * 4;
    int al = lane & 15;          // fragment row lane
    int kl = (lane >> 4) * 8;    // k-element offset within 32-chunk
    int qr = (lane >> 4) * 4;    // output-row base for this lane

    const int ns[4]   = {512, 64, 8, 1};
    const int offs[4] = {73, 9, 1, 0};

    for (int li = 0; li < 4; ++li) {
        int n = ns[li], off = offs[li];

        if (li > 0) {
            // gx phase: gx[m][1536] = enc16[m] . Wih^T + b_ih, m < M = n*8
            int M = n * 8, MT = (M + 15) >> 4;
            for (int job = wave; job < MT * 96; job += nw) {
                int mt = job / 96, jt = job % 96;
                int ar = mt * 16 + al; if (ar >= M) ar = M - 1;
                const u16* Ap = enc16 + (long long)ar * HID;
                const u16* Bp = Wih16 + (long long)(jt * 16 + al) * HID;
                f32x4 acc = (f32x4){0.f, 0.f, 0.f, 0.f};
#pragma unroll 4
                for (int kt = 0; kt < 16; ++kt) {
                    bf16x8 a = *(const bf16x8*)(Ap + kt * 32 + kl);
                    bf16x8 b = *(const bf16x8*)(Bp + kt * 32 + kl);
                    acc = __builtin_amdgcn_mfma_f32_16x16x32_bf16(a, b, acc, 0, 0, 0);
                }
                int j = jt * 16 + al;
                float bias = b_ih[j];
#pragma unroll
                for (int q = 0; q < 4; ++q) {
                    int r = mt * 16 + qr + q;
                    if (r < M) gx[(long long)r * 1536 + j] = f2bf(acc[q] + bias);
                }
            }
            gg.sync();
        }

        int MT = (n + 15) >> 4;
        for (int t = 0; t < 8; ++t) {
            for (int job = wave; job < MT * 32; job += nw) {
                int mt = job >> 5, ju = job & 31;
                f32x4 a0 = (f32x4){0.f, 0.f, 0.f, 0.f}, a1 = a0, a2 = a0;
                if (t > 0) {
                    int ar = mt * 16 + al; if (ar >= n) ar = n - 1;
                    const u16* Ap = H16 + (long long)ar * HID;
                    const u16* B0 = Whh16 + (long long)(ju * 16 + al) * HID;
                    const u16* B1 = B0 + (long long)HID * HID;
                    const u16* B2 = B1 + (long long)HID * HID;
#pragma unroll 4
                    for (int kt = 0; kt < 16; ++kt) {
                        bf16x8 a = *(const bf16x8*)(Ap + kt * 32 + kl);
                        a0 = __builtin_amdgcn_mfma_f32_16x16x32_bf16(a, *(const bf16x8*)(B0 + kt * 32 + kl), a0, 0, 0, 0);
                        a1 = __builtin_amdgcn_mfma_f32_16x16x32_bf16(a, *(const bf16x8*)(B1 + kt * 32 + kl), a1, 0, 0, 0);
                        a2 = __builtin_amdgcn_mfma_f32_16x16x32_bf16(a, *(const bf16x8*)(B2 + kt * 32 + kl), a2, 0, 0, 0);
                    }
                }
                int j = ju * 16 + al;
                float bhr = b_hh[j], bhz = b_hh[HID + j], bhn = b_hh[2 * HID + j];
#pragma unroll
                for (int q = 0; q < 4; ++q) {
                    int r = mt * 16 + qr + q;
                    if (r < n) {
                        long long gb = ((long long)(r * 8 + t)) * 1536 + j;
                        float xr = bf2f(gx[gb]), xz = bf2f(gx[gb + 512]), xn = bf2f(gx[gb + 1024]);
                        float rr = sigm(xr + a0[q] + bhr);
                        float zz = sigm(xz + a1[q] + bhz);
                        float cand = tanhf(xn + rr * (a2[q] + bhn));
                        float hp = (t > 0) ? Hf[(long long)r * HID + j] : 0.f;
                        float hnew = (1.f - zz) * cand + zz * hp;
                        Hf[(long long)r * HID + j] = hnew;
                        H16[(long long)r * HID + j] = f2bf(hnew);
                    }
                }
            }
            gg.sync();
        }

        // combine: enc16[p] = bf16(tanh(Pe[nt[off+p]] + h[p] . Wch^T))
        for (int job = wave; job < MT * 32; job += nw) {
            int mt = job >> 5, ju = job & 31;
            int ar = mt * 16 + al; if (ar >= n) ar = n - 1;
            const u16* Ap = H16 + (long long)ar * HID;
            const u16* Bp = Wch16 + (long long)(ju * 16 + al) * HID;
            f32x4 acc = (f32x4){0.f, 0.f, 0.f, 0.f};
#pragma unroll 4
            for (int kt = 0; kt < 16; ++kt) {
                bf16x8 a = *(const bf16x8*)(Ap + kt * 32 + kl);
                bf16x8 b = *(const bf16x8*)(Bp + kt * 32 + kl);
                acc = __builtin_amdgcn_mfma_f32_16x16x32_bf16(a, b, acc, 0, 0, 0);
            }
            int j = ju * 16 + al;
#pragma unroll
            for (int q = 0; q < 4; ++q) {
                int r = mt * 16 + qr + q;
                if (r < n) {
                    int tv = nt[off + r];
                    float v = tanhf(Pe[(long long)tv * HID + j] + acc[q]);
                    enc16[(long long)r * HID + j] = f2bf(v);
                    if (n == 1 && r == 0 && outf) outf[j] = v;
                }
            }
        }
        if (li < 3) gg.sync();
    }
}

// ---------------------------------------------------------------------------
extern "C" void kernel_launch(void* const* d_in, const int* in_sizes, int n_in,
                              void* d_out, int out_size, void* d_ws, size_t ws_size,
                              hipStream_t stream) {
    const int*   nt   = (const int*)d_in[0];
    const float* emb  = (const float*)d_in[1];
    const float* Wc_w = (const float*)d_in[2];
    const float* Wc_b = (const float*)d_in[3];
    const float* W_ih = (const float*)d_in[4];
    const float* W_hh = (const float*)d_in[5];
    const float* b_ih = (const float*)d_in[6];
    const float* b_hh = (const float*)d_in[7];

    uint8_t* p = (uint8_t*)d_ws;
    u16*   gx16  = (u16*)p;   p += (size_t)32768 * 1536 * 2;   // 96 MB
    u16*   enc16 = (u16*)p;   p += (size_t)4096 * HID * 2;
    float* hwfA  = (float*)p; p += (size_t)4096 * HID * 4;
    float* hwfB  = (float*)p; p += (size_t)4096 * HID * 4;
    u16*   hw16A = (u16*)p;   p += (size_t)4096 * HID * 2;
    u16*   hw16B = (u16*)p;   p += (size_t)4096 * HID * 2;
    u16*   Wih16 = (u16*)p;   p += (size_t)3 * HID * HID * 2;
    u16*   Whh16 = (u16*)p;   p += (size_t)3 * HID * HID * 2;
    u16*   Wch16 = (u16*)p;   p += (size_t)HID * HID * 2;
    float* Pe    = (float*)p; p += (size_t)20 * HID * 4;
    u16*   PeT16 = (u16*)p;   p += (size_t)20 * HID * 2;

    conv_w_kernel<<<1024, 256, 0, stream>>>(W_ih, W_hh, Wc_w, Wih16, Whh16, Wch16);
    pe_kernel<<<20, 512, 0, stream>>>(emb, Wc_w, Wc_b, Pe, PeT16);

    // ---- level 4 (n = 4096): full-grid dispatches ----
    {
        int n = 4096, M = 32768;
        dim3 ggrid(24, (M + 127) / 128);
        gx_gemm<true><<<ggrid, 256, 0, stream>>>(nullptr, PeT16, nt, Wih16, b_ih, gx16, M);
        dim3 sgrid((n + 63) / 64, 8);
        for (int t = 0; t < 8; ++t) {
            const float* sf  = (t & 1) ? hwfA : hwfB;
            const u16*   s16 = (t & 1) ? hw16A : hw16B;
            float*       df  = (t & 1) ? hwfB : hwfA;
            u16*         d16 = (t & 1) ? hw16B : hw16A;
            gru_step_h<<<sgrid, 256, 0, stream>>>(gx16, t, sf, s16, df, d16,
                                                  Whh16, b_hh, n, t > 0);
        }
        combine_mfma<<<sgrid, 256, 0, stream>>>(hw16B, Wch16, nt, 585, Pe, enc16, n);
    }

    // ---- level 3 gx (M = 4096): full-grid dispatch ----
    {
        int M = 4096;
        dim3 ggrid(24, (M + 127) / 128);
        gx_gemm<false><<<ggrid, 256, 0, stream>>>(enc16, nullptr, nt, Wih16, b_ih, gx16, M);
    }

    // ---- cooperative tail: levels 3..0 ----
    {
        float* outp = (float*)d_out;
        float* Hf   = hwfA;
        u16*   H16  = hw16A;
        void* args[] = { (void*)&gx16, (void*)&Wih16, (void*)&Whh16, (void*)&Wch16,
                         (void*)&b_ih, (void*)&b_hh, (void*)&nt, (void*)&Pe,
                         (void*)&enc16, (void*)&Hf, (void*)&H16, (void*)&outp };
        hipLaunchCooperativeKernel((const void*)tail_kernel, dim3(128), dim3(256),
                                   args, 0, stream);
    }
}

// Round 7
// 684.073 us; speedup vs baseline: 1.8549x; 1.8549x over previous
//
#include <hip/hip_runtime.h>
#include <hip/hip_bf16.h>
#include <math.h>

#define HID 512
#define WCW_LD 576
#define LEAF 4681

typedef unsigned short u16;
typedef __attribute__((ext_vector_type(8))) short bf16x8;
typedef __attribute__((ext_vector_type(4))) float f32x4;

__device__ __forceinline__ u16 f2bf(float f) {
    union { float f; unsigned u; } x; x.f = f;
    unsigned r = x.u + 0x7fffu + ((x.u >> 16) & 1u);
    return (u16)(r >> 16);
}
__device__ __forceinline__ float bf2f(u16 b) {
    union { unsigned u; float f; } x; x.u = ((unsigned)b) << 16; return x.f;
}
__device__ __forceinline__ float sigm(float x) { return 1.f / (1.f + expf(-x)); }

// XOR swizzle within 128-B windows (row stride multiple of 128 B)
__device__ __forceinline__ int swz(int row, int byte) { return byte ^ ((row & 7) << 4); }

// ---------------------------------------------------------------------------
// Pe[v][j] = emb[v].Wc_e[j] + Wc_b[j]  (fp32) ; PeT16 = bf16(tanh(Pe))
__global__ void pe_kernel(const float* __restrict__ emb, const float* __restrict__ Wc_w,
                          const float* __restrict__ Wc_b, float* __restrict__ Pe,
                          u16* __restrict__ PeT16) {
    int v = blockIdx.x, j = threadIdx.x;
    __shared__ float e[64];
    if (threadIdx.x < 64) e[threadIdx.x] = emb[v * 64 + threadIdx.x];
    __syncthreads();
    float acc = Wc_b[j];
    const float* w = Wc_w + (long long)j * WCW_LD;
#pragma unroll 8
    for (int k = 0; k < 64; ++k) acc += e[k] * w[k];
    Pe[v * HID + j] = acc;
    PeT16[v * HID + j] = f2bf(tanhf(acc));
}

__global__ void conv_w_kernel(const float* __restrict__ W_ih, const float* __restrict__ W_hh,
                              const float* __restrict__ Wc_w,
                              u16* __restrict__ Wih16, u16* __restrict__ Whh16,
                              u16* __restrict__ Wch16) {
    int idx = blockIdx.x * blockDim.x + threadIdx.x;
    int stride = gridDim.x * blockDim.x;
    for (int i = idx; i < 3 * HID * HID; i += stride) {
        Wih16[i] = f2bf(W_ih[i]);
        Whh16[i] = f2bf(W_hh[i]);
    }
    for (int i = idx; i < HID * HID; i += stride) {
        int j = i >> 9, k = i & 511;
        Wch16[i] = f2bf(Wc_w[(long long)j * WCW_LD + 64 + k]);
    }
}

// ---------------------------------------------------------------------------
// Gx20[v][j'] = PeT16[v] . Wih16[j'] + b_ih[j']   (fp32, 20 x 1536)
__global__ __launch_bounds__(256)
void gx20_kernel(const u16* __restrict__ PeT16, const u16* __restrict__ Wih16,
                 const float* __restrict__ b_ih, float* __restrict__ Gx20) {
    int v = blockIdx.x;
    int j = blockIdx.y * 256 + threadIdx.x;   // 0..1535
    const u16* a = PeT16 + v * HID;
    const u16* b = Wih16 + (long long)j * HID;
    float acc = b_ih[j];
    for (int k = 0; k < HID; k += 8) {
        bf16x8 av = *(const bf16x8*)(a + k);
        bf16x8 bv = *(const bf16x8*)(b + k);
#pragma unroll
        for (int i = 0; i < 8; ++i) acc += bf2f((u16)av[i]) * bf2f((u16)bv[i]);
    }
    Gx20[v * 1536 + j] = acc;
}

// H1[v] = GRU step-0 output given gx = Gx20[v]  (h_prev = 0)
__global__ void h1_kernel(const float* __restrict__ Gx20, const float* __restrict__ b_hh,
                          float* __restrict__ H1f, u16* __restrict__ H1_16) {
    int v = blockIdx.x, j = threadIdx.x;
    float xr = Gx20[v * 1536 + j], xz = Gx20[v * 1536 + 512 + j], xn = Gx20[v * 1536 + 1024 + j];
    float r = sigm(xr + b_hh[j]);
    float z = sigm(xz + b_hh[HID + j]);
    float cand = tanhf(xn + r * b_hh[2 * HID + j]);
    float h = (1.f - z) * cand;
    H1f[v * HID + j] = h;
    H1_16[v * HID + j] = f2bf(h);
}

// ---------------------------------------------------------------------------
// Gx = A @ Wih^T + b_ih  -> bf16 [M x 1536]. 128x64 tile, 4 waves.
// Used for levels 3..0 (A = enc16 of the level below), M = n*8 <= 4096.
__global__ __launch_bounds__(256)
void gx_gemm(const u16* __restrict__ Asrc, const u16* __restrict__ Wih16,
             const float* __restrict__ b_ih, u16* __restrict__ gx16, int M) {
    __shared__ __align__(16) uint8_t sA[128 * 128];
    __shared__ __align__(16) uint8_t sB[64 * 128];
    int tid = threadIdx.x, lane = tid & 63, w = tid >> 6;
    int j0 = blockIdx.x * 64;
    int m0 = blockIdx.y * 128;

    f32x4 acc[2][4];
#pragma unroll
    for (int m = 0; m < 2; ++m)
#pragma unroll
        for (int jf = 0; jf < 4; ++jf) acc[m][jf] = (f32x4){0.f, 0.f, 0.f, 0.f};

    for (int k0 = 0; k0 < HID; k0 += 64) {
#pragma unroll
        for (int l = 0; l < 4; ++l) {
            int e = tid + l * 256;
            int r = e >> 3, c = e & 7;
            int gm = m0 + r;
            uint4 v = make_uint4(0u, 0u, 0u, 0u);
            if (gm < M) v = *(const uint4*)(Asrc + (long long)gm * HID + k0 + c * 8);
            *(uint4*)(sA + r * 128 + swz(r, c * 16)) = v;
        }
#pragma unroll
        for (int l = 0; l < 2; ++l) {
            int e = tid + l * 256;
            int r = e >> 3, c = e & 7;
            uint4 v = *(const uint4*)(Wih16 + (long long)(j0 + r) * HID + k0 + c * 8);
            *(uint4*)(sB + r * 128 + swz(r, c * 16)) = v;
        }
        __syncthreads();
#pragma unroll
        for (int ks = 0; ks < 2; ++ks) {
            int kb = ks * 64 + ((lane >> 4) << 4);
            int ar = lane & 15;
            bf16x8 a0 = *(const bf16x8*)(sA + (w * 32 + ar) * 128 + swz(ar, kb));
            bf16x8 a1 = *(const bf16x8*)(sA + (w * 32 + 16 + ar) * 128 + swz(ar, kb));
#pragma unroll
            for (int jf = 0; jf < 4; ++jf) {
                bf16x8 b = *(const bf16x8*)(sB + (jf * 16 + ar) * 128 + swz(ar, kb));
                acc[0][jf] = __builtin_amdgcn_mfma_f32_16x16x32_bf16(a0, b, acc[0][jf], 0, 0, 0);
                acc[1][jf] = __builtin_amdgcn_mfma_f32_16x16x32_bf16(a1, b, acc[1][jf], 0, 0, 0);
            }
        }
        __syncthreads();
    }

#pragma unroll
    for (int jf = 0; jf < 4; ++jf) {
        int j = j0 + jf * 16 + (lane & 15);
        float bias = b_ih[j];
#pragma unroll
        for (int m = 0; m < 2; ++m) {
#pragma unroll
            for (int q = 0; q < 4; ++q) {
                int row = m0 + w * 32 + m * 16 + (lane >> 4) * 4 + q;
                if (row < M) gx16[(long long)row * 1536 + j] = f2bf(acc[m][jf][q] + bias);
            }
        }
    }
}

// ---------------------------------------------------------------------------
// h-side GRU step, MFMA 64x64 tile.
// GX_TABLE: gx row = Gx20[nt[LEAF + p*8 + t]] (fp32 table; level 4).
// H_TABLE : hsrc = H1[nt[LEAF + p*8]] (t==1 at level 4).
template<int GX_TABLE, int H_TABLE>
__global__ __launch_bounds__(256, 4)
void gru_step_h(const u16* __restrict__ hsrc16, const float* __restrict__ hsrc_f,
                const u16* __restrict__ H1_16, const float* __restrict__ H1f,
                const float* __restrict__ Gx20, const u16* __restrict__ gx16, int t,
                const int* __restrict__ nt,
                float* __restrict__ hdst_f, u16* __restrict__ hdst16,
                const u16* __restrict__ Whh16, const float* __restrict__ b_hh, int n) {
    __shared__ __align__(16) uint8_t sm[4][8192];
    int tid = threadIdx.x;
    int p0 = blockIdx.x * 64, j0 = blockIdx.y * 64;
    int lane = tid & 63, w = tid >> 6, wr = w >> 1, wc = w & 1;

    f32x4 acc[3][2][2];
#pragma unroll
    for (int g = 0; g < 3; ++g)
#pragma unroll
        for (int i = 0; i < 2; ++i)
#pragma unroll
            for (int j = 0; j < 2; ++j) acc[g][i][j] = (f32x4){0.f, 0.f, 0.f, 0.f};

    for (int kt = 0; kt < 8; ++kt) {
        int k0 = kt * 64;
#pragma unroll
        for (int l = 0; l < 2; ++l) {
            int e = tid + l * 256;
            int r = e >> 3, c = e & 7;
            int p = p0 + r;
            uint4 v = make_uint4(0u, 0u, 0u, 0u);
            if (p < n) {
                const u16* src = H_TABLE ? (H1_16 + (long long)nt[LEAF + p * 8] * HID)
                                         : (hsrc16 + (long long)p * HID);
                v = *(const uint4*)(src + k0 + c * 8);
            }
            *(uint4*)(sm[0] + r * 128 + swz(r, c * 16)) = v;
        }
#pragma unroll
        for (int g = 0; g < 3; ++g) {
#pragma unroll
            for (int l = 0; l < 2; ++l) {
                int e = tid + l * 256;
                int r = e >> 3, c = e & 7;
                uint4 v = *(const uint4*)(Whh16 + (long long)(g * HID + j0 + r) * HID + k0 + c * 8);
                *(uint4*)(sm[1 + g] + r * 128 + swz(r, c * 16)) = v;
            }
        }
        __syncthreads();
#pragma unroll
        for (int s = 0; s < 2; ++s) {
            int kb = s * 64 + ((lane >> 4) << 4);
            int ar = lane & 15;
            bf16x8 a0 = *(const bf16x8*)(sm[0] + (wr * 32 + ar) * 128 + swz(ar, kb));
            bf16x8 a1 = *(const bf16x8*)(sm[0] + (wr * 32 + 16 + ar) * 128 + swz(ar, kb));
#pragma unroll
            for (int g = 0; g < 3; ++g) {
#pragma unroll
                for (int jf = 0; jf < 2; ++jf) {
                    bf16x8 b = *(const bf16x8*)(sm[1 + g] + (wc * 32 + jf * 16 + ar) * 128 + swz(ar, kb));
                    acc[g][0][jf] = __builtin_amdgcn_mfma_f32_16x16x32_bf16(a0, b, acc[g][0][jf], 0, 0, 0);
                    acc[g][1][jf] = __builtin_amdgcn_mfma_f32_16x16x32_bf16(a1, b, acc[g][1][jf], 0, 0, 0);
                }
            }
        }
        __syncthreads();
    }

#pragma unroll
    for (int i = 0; i < 2; ++i) {
#pragma unroll
        for (int jf = 0; jf < 2; ++jf) {
            int jj = j0 + wc * 32 + jf * 16 + (lane & 15);
            float bhr = b_hh[jj], bhz = b_hh[HID + jj], bhn = b_hh[2 * HID + jj];
#pragma unroll
            for (int q = 0; q < 4; ++q) {
                int p = p0 + wr * 32 + i * 16 + (lane >> 4) * 4 + q;
                if (p >= n) continue;
                float xr, xz, xn;
                if (GX_TABLE) {
                    int v = nt[LEAF + p * 8 + t];
                    const float* gp = Gx20 + (long long)v * 1536 + jj;
                    xr = gp[0]; xz = gp[512]; xn = gp[1024];
                } else {
                    long long gb = ((long long)(p * 8 + t)) * 1536 + jj;
                    xr = bf2f(gx16[gb]); xz = bf2f(gx16[gb + 512]); xn = bf2f(gx16[gb + 1024]);
                }
                float hp = H_TABLE ? H1f[(long long)nt[LEAF + p * 8] * HID + jj]
                                   : hsrc_f[(long long)p * HID + jj];
                float r = sigm(xr + acc[0][i][jf][q] + bhr);
                float z = sigm(xz + acc[1][i][jf][q] + bhz);
                float cand = tanhf(xn + r * (acc[2][i][jf][q] + bhn));
                float hnew = (1.f - z) * cand + z * hp;
                hdst_f[(long long)p * HID + jj] = hnew;
                hdst16[(long long)p * HID + jj] = f2bf(hnew);
            }
        }
    }
}

// ---------------------------------------------------------------------------
// MFMA combine (n >= 512): out16 = bf16(tanh(Pe[nt] + h @ Wc_h^T))
__global__ __launch_bounds__(256, 4)
void combine_mfma(const u16* __restrict__ enc_in, const u16* __restrict__ Wch16,
                  const int* __restrict__ nt, int off, const float* __restrict__ Pe,
                  u16* __restrict__ out16, int n) {
    __shared__ __align__(16) uint8_t sm[2][8192];
    int tid = threadIdx.x;
    int p0 = blockIdx.x * 64, j0 = blockIdx.y * 64;
    int lane = tid & 63, w = tid >> 6, wr = w >> 1, wc = w & 1;

    f32x4 acc[2][2];
#pragma unroll
    for (int i = 0; i < 2; ++i)
#pragma unroll
        for (int j = 0; j < 2; ++j) acc[i][j] = (f32x4){0.f, 0.f, 0.f, 0.f};

    for (int kt = 0; kt < 8; ++kt) {
        int k0 = kt * 64;
#pragma unroll
        for (int l = 0; l < 2; ++l) {
            int e = tid + l * 256;
            int r = e >> 3, c = e & 7;
            uint4 v = make_uint4(0u, 0u, 0u, 0u);
            if (p0 + r < n) v = *(const uint4*)(enc_in + (long long)(p0 + r) * HID + k0 + c * 8);
            *(uint4*)(sm[0] + r * 128 + swz(r, c * 16)) = v;
        }
#pragma unroll
        for (int l = 0; l < 2; ++l) {
            int e = tid + l * 256;
            int r = e >> 3, c = e & 7;
            uint4 v = *(const uint4*)(Wch16 + (long long)(j0 + r) * HID + k0 + c * 8);
            *(uint4*)(sm[1] + r * 128 + swz(r, c * 16)) = v;
        }
        __syncthreads();
#pragma unroll
        for (int s = 0; s < 2; ++s) {
            int kb = s * 64 + ((lane >> 4) << 4);
            int ar = lane & 15;
            bf16x8 a0 = *(const bf16x8*)(sm[0] + (wr * 32 + ar) * 128 + swz(ar, kb));
            bf16x8 a1 = *(const bf16x8*)(sm[0] + (wr * 32 + 16 + ar) * 128 + swz(ar, kb));
#pragma unroll
            for (int j = 0; j < 2; ++j) {
                bf16x8 b = *(const bf16x8*)(sm[1] + (wc * 32 + j * 16 + ar) * 128 + swz(ar, kb));
                acc[0][j] = __builtin_amdgcn_mfma_f32_16x16x32_bf16(a0, b, acc[0][j], 0, 0, 0);
                acc[1][j] = __builtin_amdgcn_mfma_f32_16x16x32_bf16(a1, b, acc[1][j], 0, 0, 0);
            }
        }
        __syncthreads();
    }

#pragma unroll
    for (int i = 0; i < 2; ++i) {
#pragma unroll
        for (int j = 0; j < 2; ++j) {
            int jj = j0 + wc * 32 + j * 16 + (lane & 15);
#pragma unroll
            for (int q = 0; q < 4; ++q) {
                int p = p0 + wr * 32 + i * 16 + (lane >> 4) * 4 + q;
                if (p >= n) continue;
                int tv = nt[off + p];
                float v = tanhf(Pe[(long long)tv * HID + jj] + acc[i][j][q]);
                out16[(long long)p * HID + jj] = f2bf(v);
            }
        }
    }
}

// ---------------------------------------------------------------------------
// Step t=0 (h=0, no GEMM): h1 = (1-z)*cand from gx row. One thread per (p,j).
__global__ __launch_bounds__(256)
void t0_simt(const u16* __restrict__ gx16, const float* __restrict__ b_hh,
             float* __restrict__ hdst_f, u16* __restrict__ hdst16, int n) {
    int idx = blockIdx.x * 256 + threadIdx.x;
    int p = idx >> 9, j = idx & 511;
    if (p >= n) return;
    long long gb = ((long long)(p * 8)) * 1536 + j;
    float xr = bf2f(gx16[gb]), xz = bf2f(gx16[gb + 512]), xn = bf2f(gx16[gb + 1024]);
    float r = sigm(xr + b_hh[j]);
    float z = sigm(xz + b_hh[HID + j]);
    float cand = tanhf(xn + r * b_hh[2 * HID + j]);
    float h = (1.f - z) * cand;
    hdst_f[(long long)p * HID + j] = h;
    hdst16[(long long)p * HID + j] = f2bf(h);
}

// ---------------------------------------------------------------------------
// K-split SIMT GRU step (n <= 64): thread per (p, j, kc), kc = 4 chunks of 128.
// Partials reduced via shfl_xor within the 4-lane group.
__global__ __launch_bounds__(256)
void step_simt(const u16* __restrict__ gx16, int t,
               const float* __restrict__ hsrc_f, const u16* __restrict__ hsrc16,
               float* __restrict__ hdst_f, u16* __restrict__ hdst16,
               const u16* __restrict__ Whh16, const float* __restrict__ b_hh, int n) {
    int idx = blockIdx.x * 256 + threadIdx.x;
    int kc = idx & 3, pj = idx >> 2;
    int p = pj >> 9, j = pj & 511;
    if (p >= n) return;
    const u16* hp16 = hsrc16 + (long long)p * HID + kc * 128;
    const u16* w0 = Whh16 + (long long)j * HID + kc * 128;
    const u16* w1 = w0 + (long long)HID * HID;
    const u16* w2 = w1 + (long long)HID * HID;
    float a0 = 0.f, a1 = 0.f, a2 = 0.f;
#pragma unroll 4
    for (int k = 0; k < 128; k += 8) {
        bf16x8 hv = *(const bf16x8*)(hp16 + k);
        bf16x8 v0 = *(const bf16x8*)(w0 + k);
        bf16x8 v1 = *(const bf16x8*)(w1 + k);
        bf16x8 v2 = *(const bf16x8*)(w2 + k);
#pragma unroll
        for (int i = 0; i < 8; ++i) {
            float hh = bf2f((u16)hv[i]);
            a0 += hh * bf2f((u16)v0[i]);
            a1 += hh * bf2f((u16)v1[i]);
            a2 += hh * bf2f((u16)v2[i]);
        }
    }
    a0 += __shfl_xor(a0, 1); a0 += __shfl_xor(a0, 2);
    a1 += __shfl_xor(a1, 1); a1 += __shfl_xor(a1, 2);
    a2 += __shfl_xor(a2, 1); a2 += __shfl_xor(a2, 2);
    if (kc == 0) {
        long long gb = ((long long)(p * 8 + t)) * 1536 + j;
        float xr = bf2f(gx16[gb]), xz = bf2f(gx16[gb + 512]), xn = bf2f(gx16[gb + 1024]);
        float r = sigm(xr + a0 + b_hh[j]);
        float z = sigm(xz + a1 + b_hh[HID + j]);
        float cand = tanhf(xn + r * (a2 + b_hh[2 * HID + j]));
        float hp = hsrc_f[(long long)p * HID + j];
        float hnew = (1.f - z) * cand + z * hp;
        hdst_f[(long long)p * HID + j] = hnew;
        hdst16[(long long)p * HID + j] = f2bf(hnew);
    }
}

// ---------------------------------------------------------------------------
// K-split SIMT combine (n <= 64)
__global__ __launch_bounds__(256)
void combine_simt(const u16* __restrict__ h16, const u16* __restrict__ Wch16,
                  const int* __restrict__ nt, int off, const float* __restrict__ Pe,
                  u16* __restrict__ enc16, float* __restrict__ outf, int n) {
    int idx = blockIdx.x * 256 + threadIdx.x;
    int kc = idx & 3, pj = idx >> 2;
    int p = pj >> 9, j = pj & 511;
    if (p >= n) return;
    const u16* hp = h16 + (long long)p * HID + kc * 128;
    const u16* wr = Wch16 + (long long)j * HID + kc * 128;
    float a = 0.f;
#pragma unroll 4
    for (int k = 0; k < 128; k += 8) {
        bf16x8 hv = *(const bf16x8*)(hp + k);
        bf16x8 wv = *(const bf16x8*)(wr + k);
#pragma unroll
        for (int i = 0; i < 8; ++i) a += bf2f((u16)hv[i]) * bf2f((u16)wv[i]);
    }
    a += __shfl_xor(a, 1); a += __shfl_xor(a, 2);
    if (kc == 0) {
        int tv = nt[off + p];
        float v = tanhf(Pe[(long long)tv * HID + j] + a);
        enc16[(long long)p * HID + j] = f2bf(v);
        if (outf) outf[(long long)p * HID + j] = v;
    }
}

// ---------------------------------------------------------------------------
extern "C" void kernel_launch(void* const* d_in, const int* in_sizes, int n_in,
                              void* d_out, int out_size, void* d_ws, size_t ws_size,
                              hipStream_t stream) {
    const int*   nt   = (const int*)d_in[0];
    const float* emb  = (const float*)d_in[1];
    const float* Wc_w = (const float*)d_in[2];
    const float* Wc_b = (const float*)d_in[3];
    const float* W_ih = (const float*)d_in[4];
    const float* W_hh = (const float*)d_in[5];
    const float* b_ih = (const float*)d_in[6];
    const float* b_hh = (const float*)d_in[7];

    uint8_t* p = (uint8_t*)d_ws;
    u16*   gx16  = (u16*)p;   p += (size_t)4096 * 1536 * 2;    // 12.6 MB (levels 3..0)
    u16*   enc16 = (u16*)p;   p += (size_t)4096 * HID * 2;
    float* hf[2]; u16* h16[2];
    hf[0]  = (float*)p; p += (size_t)4096 * HID * 4;
    hf[1]  = (float*)p; p += (size_t)4096 * HID * 4;
    h16[0] = (u16*)p;   p += (size_t)4096 * HID * 2;
    h16[1] = (u16*)p;   p += (size_t)4096 * HID * 2;
    u16*   Wih16 = (u16*)p;   p += (size_t)3 * HID * HID * 2;
    u16*   Whh16 = (u16*)p;   p += (size_t)3 * HID * HID * 2;
    u16*   Wch16 = (u16*)p;   p += (size_t)HID * HID * 2;
    float* Pe    = (float*)p; p += (size_t)20 * HID * 4;
    u16*   PeT16 = (u16*)p;   p += (size_t)20 * HID * 2;
    float* Gx20  = (float*)p; p += (size_t)20 * 1536 * 4;
    float* H1f   = (float*)p; p += (size_t)20 * HID * 4;
    u16*   H1_16 = (u16*)p;   p += (size_t)20 * HID * 2;

    // prologue
    conv_w_kernel<<<1024, 256, 0, stream>>>(W_ih, W_hh, Wc_w, Wih16, Whh16, Wch16);
    pe_kernel<<<20, 512, 0, stream>>>(emb, Wc_w, Wc_b, Pe, PeT16);
    gx20_kernel<<<dim3(20, 6), 256, 0, stream>>>(PeT16, Wih16, b_ih, Gx20);
    h1_kernel<<<20, 512, 0, stream>>>(Gx20, b_hh, H1f, H1_16);

    // ---- level 4 (n = 4096): t=0 folded into H1 table; 7 MFMA steps ----
    {
        int n = 4096;
        dim3 sgrid(n / 64, 8);
        // t = 1: hsrc from H1 table
        gru_step_h<1, 1><<<sgrid, 256, 0, stream>>>(nullptr, nullptr, H1_16, H1f,
                                                    Gx20, nullptr, 1, nt,
                                                    hf[0], h16[0], Whh16, b_hh, n);
        int cur = 0;
        for (int t = 2; t < 8; ++t) {
            gru_step_h<1, 0><<<sgrid, 256, 0, stream>>>(h16[cur], hf[cur], nullptr, nullptr,
                                                        Gx20, nullptr, t, nt,
                                                        hf[cur ^ 1], h16[cur ^ 1], Whh16, b_hh, n);
            cur ^= 1;
        }
        combine_mfma<<<sgrid, 256, 0, stream>>>(h16[cur], Wch16, nt, 585, Pe, enc16, n);
    }

    // ---- levels 3..0 ----
    const int sizes[4] = {512, 64, 8, 1};
    const int offs[4]  = {73, 9, 1, 0};
    for (int li = 0; li < 4; ++li) {
        int n = sizes[li], off = offs[li];
        int M = n * 8;
        dim3 ggrid(24, (M + 127) / 128);
        gx_gemm<<<ggrid, 256, 0, stream>>>(enc16, Wih16, b_ih, gx16, M);

        t0_simt<<<n * 2, 256, 0, stream>>>(gx16, b_hh, hf[0], h16[0], n);
        int cur = 0;
        if (n >= 512) {
            dim3 sgrid(n / 64, 8);
            for (int t = 1; t < 8; ++t) {
                gru_step_h<0, 0><<<sgrid, 256, 0, stream>>>(h16[cur], hf[cur], nullptr, nullptr,
                                                            nullptr, gx16, t, nt,
                                                            hf[cur ^ 1], h16[cur ^ 1], Whh16, b_hh, n);
                cur ^= 1;
            }
            combine_mfma<<<sgrid, 256, 0, stream>>>(h16[cur], Wch16, nt, off, Pe, enc16, n);
        } else {
            for (int t = 1; t < 8; ++t) {
                step_simt<<<n * 8, 256, 0, stream>>>(gx16, t, hf[cur], h16[cur],
                                                     hf[cur ^ 1], h16[cur ^ 1], Whh16, b_hh, n);
                cur ^= 1;
            }
            combine_simt<<<n * 8, 256, 0, stream>>>(h16[cur], Wch16, nt, off, Pe, enc16,
                                                    (li == 3) ? (float*)d_out : (float*)0, n);
        }
    }
}